// Round 1
// baseline (402.997 us; speedup 1.0000x reference)
//
#include <hip/hip_runtime.h>
#include <hip/hip_bf16.h>

// Problem constants (fixed by setup_inputs): fp32 inputs/outputs.
constexpr int Bn = 4;
constexpr int Tn = 4096;
constexpr int Dn = 256;
constexpr int NT = Tn / 64;             // 64 t-tiles per batch
constexpr int NTRI = NT * (NT + 1) / 2; // 2080 lower-tri 64x64 tiles per batch

using ushort = unsigned short;
typedef short short8 __attribute__((ext_vector_type(8)));
typedef float f32x4 __attribute__((ext_vector_type(4)));
typedef float f32x4v __attribute__((ext_vector_type(4)));

__device__ __forceinline__ ushort f2bu(float f) {
    __hip_bfloat16 h = __float2bfloat16(f);
    return __builtin_bit_cast(unsigned short, h);
}
__device__ __forceinline__ void gld_lds16(const ushort* g, ushort* l) {
    __builtin_amdgcn_global_load_lds((const __attribute__((address_space(1))) void*)g,
                                     (__attribute__((address_space(3))) void*)l,
                                     16, 0, 0);
}
__device__ __forceinline__ float dis_of(float a) { return rsqrtf(a + 1e-6f); }

// ---------------- Kernel 1: lower-tri tile pass ----------------
// One block per lower-triangular 64x64 tile. Reads fp32 A tile (136 MB total,
// non-temporal: A is dead after this read, keep Apk resident in LLC),
// atomically accumulates row sums (and col sums for off-diag tiles, using
// symmetry) into acc[b][t], writes bf16 packed tile (diag causally masked).
__global__ __launch_bounds__(256) void tri_pass_kernel(
    const float* __restrict__ A, float* __restrict__ acc, ushort* __restrict__ Apk) {
    __shared__ float tile[64][68];      // float4-aligned stride, conflict-benign
    int bid = blockIdx.x;
    int b = bid / NTRI;
    int r = bid - b * NTRI;
    int it = (int)((sqrtf(8.f * r + 1.f) - 1.f) * 0.5f);
    while ((it + 1) * (it + 2) / 2 <= r) ++it;
    while (it * (it + 1) / 2 > r) --it;
    int kt = r - it * (it + 1) / 2;
    int t0 = it * 64, s0 = kt * 64;
    bool diag = (kt == it);

    int tid = threadIdx.x;
    int i = tid >> 2;                   // row 0..63
    int c0 = (tid & 3) * 16;            // col group (16 floats = 64B per thread)

    const float* g = A + ((size_t)(b * Tn + t0 + i) * Tn + s0 + c0);
    f32x4v v[4];
#pragma unroll
    for (int q = 0; q < 4; ++q) v[q] = __builtin_nontemporal_load((const f32x4v*)(g + 4 * q));

    float f[16];
#pragma unroll
    for (int q = 0; q < 4; ++q) {
        f[4 * q + 0] = v[q][0]; f[4 * q + 1] = v[q][1];
        f[4 * q + 2] = v[q][2]; f[4 * q + 3] = v[q][3];
    }
    float rp = 0.f;
#pragma unroll
    for (int e = 0; e < 16; ++e) rp += f[e];
    rp += __shfl_xor(rp, 1, 64);
    rp += __shfl_xor(rp, 2, 64);
    if ((tid & 3) == 0) atomicAdd(&acc[b * Tn + t0 + i], rp);

#pragma unroll
    for (int q = 0; q < 4; ++q) *(f32x4v*)&tile[i][c0 + 4 * q] = v[q];

    ushort* tb = Apk + (size_t)b * NTRI * 4096 + (size_t)(it * (it + 1) / 2 + kt) * 4096;
    unsigned w[8];
#pragma unroll
    for (int e = 0; e < 8; ++e) {
        float lo = f[2 * e], hi = f[2 * e + 1];
        if (diag) {
            if (c0 + 2 * e > i)     lo = 0.f;
            if (c0 + 2 * e + 1 > i) hi = 0.f;
        }
        w[e] = (unsigned)f2bu(lo) | ((unsigned)f2bu(hi) << 16);
    }
    *(uint4*)(tb + i * 64 + c0)     = make_uint4(w[0], w[1], w[2], w[3]);
    *(uint4*)(tb + i * 64 + c0 + 8) = make_uint4(w[4], w[5], w[6], w[7]);

    if (!diag) {
        __syncthreads();
        int j = tid & 63, p = tid >> 6;
        float cp = 0.f;
#pragma unroll
        for (int q = 0; q < 16; ++q) cp += tile[p * 16 + q][j];
        atomicAdd(&acc[b * Tn + s0 + j], cp);
    }
}

// ---------------- Kernel 2: kT[b][d][s] = bf16(dis(acc[b,s]) * k[b][s][d]) ----------------
__global__ __launch_bounds__(256) void scale_transpose_kernel(
    const float* __restrict__ K, const float* __restrict__ acc, ushort* __restrict__ kT) {
    int bid = blockIdx.x;
    int b = bid >> 8;
    int rr = bid & 255;
    int st = rr >> 2, dt = rr & 3;
    int s0 = st * 64, d0 = dt * 64;
    __shared__ ushort tile[64][72];     // padded
    int tid = threadIdx.x;
#pragma unroll
    for (int q = 0; q < 2; ++q) {
        int idx = q * 256 + tid;
        int sl = idx >> 3, dl0 = (idx & 7) * 8;
        const float* g = K + ((size_t)(b * Tn + s0 + sl) * Dn + d0 + dl0);
        float sc = dis_of(acc[b * Tn + s0 + sl]);
        float4 v0 = *(const float4*)g;
        float4 v1 = *(const float4*)(g + 4);
        tile[sl][dl0 + 0] = f2bu(v0.x * sc);
        tile[sl][dl0 + 1] = f2bu(v0.y * sc);
        tile[sl][dl0 + 2] = f2bu(v0.z * sc);
        tile[sl][dl0 + 3] = f2bu(v0.w * sc);
        tile[sl][dl0 + 4] = f2bu(v1.x * sc);
        tile[sl][dl0 + 5] = f2bu(v1.y * sc);
        tile[sl][dl0 + 6] = f2bu(v1.z * sc);
        tile[sl][dl0 + 7] = f2bu(v1.w * sc);
    }
    __syncthreads();
#pragma unroll
    for (int q = 0; q < 2; ++q) {
        int idx = q * 256 + tid;
        int dl = idx >> 3, sl0 = (idx & 7) * 8;
        unsigned w[4];
#pragma unroll
        for (int e = 0; e < 4; ++e) {
            unsigned lo = tile[sl0 + 2 * e][dl];
            unsigned hi = tile[sl0 + 2 * e + 1][dl];
            w[e] = lo | (hi << 16);
        }
        *(uint4*)(kT + ((size_t)(b * Dn + d0 + dl) * Tn + s0 + sl0)) =
            make_uint4(w[0], w[1], w[2], w[3]);
    }
}

// ---------------- Kernel 3: causal MFMA GEMM, BM=128 x BN=64, double-buffered ----------------
// out[b,t,d] = sqrt(0.5)*dis(acc[t]) * sum_{s<=t} Apk[b,t,s] * kT[b,d,s]  (fp32 out)
// - 4 waves, each owns a 64x32 sub-tile: 16 MFMA : 12 ds_read_b128 per K-step.
// - LDS XOR chunk-swizzle (pre-swizzled global src, linear gld_lds dest,
//   same XOR on ds_read) kills the stride-128B 16-way bank conflict.
// - Balanced pairing: bids 0..255 -> it2 = 31..16 (desc), bids 256..511 ->
//   it2 = 0..15 (asc). Round-robin dispatch puts bid c and c+256 on the same
//   CU -> every CU gets a constant 66 K-iterations.
__global__ __launch_bounds__(256) void gemm_causal_kernel(
    const ushort* __restrict__ Apk, const ushort* __restrict__ kT,
    const float* __restrict__ acc_in, float* __restrict__ out,
    const ushort* __restrict__ zsrc) {
    __shared__ __attribute__((aligned(16))) ushort As[2][128 * 64];  // 32 KB
    __shared__ __attribute__((aligned(16))) ushort Bs[2][64 * 64];   // 16 KB
    __shared__ float rs[128];

    int bid = blockIdx.x;
    int g = bid >> 4;                    // 0..31
    int sub = bid & 15;
    int it2 = (g < 16) ? (31 - g) : (g - 16);
    int b = sub >> 2;
    int d0 = (sub & 3) * 64;
    int itA = 2 * it2, itB = 2 * it2 + 1;
    int t0 = itA * 64;
    int nkt = 2 * it2 + 2;               // K-tiles (s up to t0+128, causal)

    int tid = threadIdx.x;
    int lane = tid & 63;
    int w = tid >> 6;
    int l15 = lane & 15;

    const ushort* ApkA = Apk + (size_t)b * NTRI * 4096 + (size_t)(itA * (itA + 1) / 2) * 4096;
    const ushort* ApkB = Apk + (size_t)b * NTRI * 4096 + (size_t)(itB * (itB + 1) / 2) * 4096;
    const size_t kTbase = (size_t)(b * Dn + d0) * Tn;

    if (tid < 128) rs[tid] = 0.70710678118654752f * dis_of(acc_in[b * Tn + t0 + tid]);

    f32x4 acc[4][2];
#pragma unroll
    for (int mi = 0; mi < 4; ++mi)
#pragma unroll
        for (int ni = 0; ni < 2; ++ni) acc[mi][ni] = (f32x4){0.f, 0.f, 0.f, 0.f};

    int mrow = (w >> 1) * 64;            // {0, 64}
    int ncol = (w & 1) * 32;             // {0, 32}

    auto stage = [&](int buf, int kt) {
        bool lastA = (kt == itB);        // top half has no tile at the last K-step
        const ushort* baseA = ApkA + (size_t)kt * 4096;
        const ushort* baseB = ApkB + (size_t)kt * 4096;
#pragma unroll
        for (int q = 0; q < 4; ++q) {
            int idx = q * 256 + tid;
            int row = idx >> 3, ch = idx & 7;
            int sch = ((ch ^ (row & 7)) << 3);           // pre-swizzled source chunk
            const ushort* src;
            if (row < 64) src = lastA ? zsrc : (baseA + row * 64 + sch);
            else          src = baseB + (size_t)(row - 64) * 64 + sch;
            gld_lds16(src, &As[buf][idx * 8]);           // linear LDS dest
        }
#pragma unroll
        for (int q = 0; q < 2; ++q) {
            int idx = q * 256 + tid;
            int n = idx >> 3, ch = idx & 7;
            int sch = ((ch ^ (n & 7)) << 3);
            gld_lds16(kT + kTbase + (size_t)n * Tn + kt * 64 + sch, &Bs[buf][idx * 8]);
        }
    };

    stage(0, 0);
    __syncthreads();

    for (int kt = 0; kt < nkt; ++kt) {
        int cur = kt & 1;
        if (kt + 1 < nkt) stage(cur ^ 1, kt + 1);
#pragma unroll
        for (int ki = 0; ki < 2; ++ki) {
            int kch = ki * 4 + (lane >> 4);              // 16B-chunk index (kc/8)
            short8 af[4];
#pragma unroll
            for (int mi = 0; mi < 4; ++mi) {
                int rrow = mrow + 16 * mi + l15;
                af[mi] = *(const short8*)&As[cur][rrow * 64 + ((kch ^ (rrow & 7)) << 3)];
            }
            short8 bfr[2];
#pragma unroll
            for (int ni = 0; ni < 2; ++ni) {
                int n = ncol + 16 * ni + l15;
                bfr[ni] = *(const short8*)&Bs[cur][n * 64 + ((kch ^ (n & 7)) << 3)];
            }
#pragma unroll
            for (int mi = 0; mi < 4; ++mi)
#pragma unroll
                for (int ni = 0; ni < 2; ++ni)
                    acc[mi][ni] = __builtin_amdgcn_mfma_f32_16x16x32_bf16(
                        af[mi], bfr[ni], acc[mi][ni], 0, 0, 0);
        }
        __syncthreads();
    }

#pragma unroll
    for (int mi = 0; mi < 4; ++mi) {
#pragma unroll
        for (int ni = 0; ni < 2; ++ni) {
            int tl = mrow + 16 * mi + (lane >> 4) * 4;
            int d = d0 + ncol + 16 * ni + l15;
#pragma unroll
            for (int r = 0; r < 4; ++r) {
                int t = t0 + tl + r;
                out[(size_t)(b * Tn + t) * Dn + d] = acc[mi][ni][r] * rs[tl + r];
            }
        }
    }
}

extern "C" void kernel_launch(void* const* d_in, const int* in_sizes, int n_in,
                              void* d_out, int out_size, void* d_ws, size_t ws_size,
                              hipStream_t stream) {
    const float* A = (const float*)d_in[0];     // A_rel fp32, (4,4096,4096)
    const float* K = (const float*)d_in[1];     // k_seq fp32, (4,4096,256)
    float* out = (float*)d_out;                 // fp32, (4,4096,256)

    float* acc = (float*)d_ws;                          // 16384 f32 = 64 KB
    ushort* kT = (ushort*)(acc + Bn * Tn);              // 8.39 MB bf16
    ushort* Apk = kT + (size_t)Bn * Dn * Tn;            // 68.2 MB packed-tri bf16
    ushort* zsrc = Apk + (size_t)Bn * NTRI * 4096;      // 256 B zero region

    hipMemsetAsync(acc, 0, Bn * Tn * sizeof(float), stream);
    hipMemsetAsync(zsrc, 0, 256, stream);
    tri_pass_kernel<<<dim3(Bn * NTRI), dim3(256), 0, stream>>>(A, acc, Apk);
    scale_transpose_kernel<<<dim3(Bn * (Tn / 64) * (Dn / 64)), dim3(256), 0, stream>>>(K, acc, kT);
    gemm_causal_kernel<<<dim3(512), dim3(256), 0, stream>>>(Apk, kT, acc, out, zsrc);
}